// Round 10
// baseline (110.323 us; speedup 1.0000x reference)
//
#include <hip/hip_runtime.h>

// YOLO-style loss: pred/target (16384, 7, 7, 14) fp32 -> scalar fp32.
// N = 14 channels: [0..4] box0 (x,y,w,h,conf), [5..9] box1, [10..13] classes.
//
// Round-10: R9 structure (1 wave/block, wave-private LDS, no barriers,
// global_load_lds staging, stride-7 ds_read_b128, plain partial stores)
// + 2-deep pipelined tiles per wave (PPB=128, 28 KB LDS): issue A(14 loads),
// issue B(14 loads), vmcnt(14) -> compute A while B flies, vmcnt(0) ->
// compute B. Halves block count (3136) and per-block fixed cost.
// Reduce kernel: 1024 threads, one float4 each (784 exact), one latency hop.

#define NPAIRS (16384 * 7 * 7 / 2)   // 401408
#define TPB 64
#define PPW 64                        // pairs per tile (per wave half)
#define PPB (2 * PPW)                 // 128 pairs per block, 2-deep pipeline
#define SLOTS (PPW * 7)               // 448 float4 slots per tensor per half
#define NBLOCKS (NPAIRS / PPB)        // 3136, exact

typedef __attribute__((address_space(3))) void lds_void;
typedef const __attribute__((address_space(1))) void glb_void;

__device__ __forceinline__ float cell_loss(const float* __restrict__ p,
                                           const float* __restrict__ t) {
    const float conf_t = t[4];
    const float coord = (conf_t > 0.0f) ? 1.0f : 0.0f;

    // target box 0
    const float tx = t[0] / 7.0f;
    const float ty = t[1] / 7.0f;
    const float tw = t[2];
    const float th = t[3];
    const float tlx = tx - 0.5f * tw, tly = ty - 0.5f * th;
    const float trx = tx + 0.5f * tw, trY = ty + 0.5f * th;
    const float area_t = (trx - tlx) * (trY - tly);

    float iou0, iou1;
    {
        const float px = p[0] / 7.0f, py = p[1] / 7.0f;
        const float pw = p[2], ph = p[3];
        const float plx = px - 0.5f * pw, ply = py - 0.5f * ph;
        const float prx = px + 0.5f * pw, prY = py + 0.5f * ph;
        const float ltx = fmaxf(plx, tlx), lty = fmaxf(ply, tly);
        const float rbx = fminf(prx, trx), rby = fminf(prY, trY);
        const float wx = fmaxf(rbx - ltx, 0.0f), wy = fmaxf(rby - lty, 0.0f);
        const float inter = wx * wy;
        const float area_p = (prx - plx) * (prY - ply);
        iou0 = inter / (area_p + area_t - inter);
    }
    {
        const float px = p[5] / 7.0f, py = p[6] / 7.0f;
        const float pw = p[7], ph = p[8];
        const float plx = px - 0.5f * pw, ply = py - 0.5f * ph;
        const float prx = px + 0.5f * pw, prY = py + 0.5f * ph;
        const float ltx = fmaxf(plx, tlx), lty = fmaxf(ply, tly);
        const float rbx = fminf(prx, trx), rby = fminf(prY, trY);
        const float wx = fmaxf(rbx - ltx, 0.0f), wy = fmaxf(rby - lty, 0.0f);
        const float inter = wx * wy;
        const float area_p = (prx - plx) * (prY - ply);
        iou1 = inter / (area_p + area_t - inter);
    }

    // jnp.argmax: first max wins -> box1 only if strictly greater.
    const bool sel1 = (iou1 > iou0);
    const float max_iou = fmaxf(iou0, iou1);

    // Branchless responsible-box select with STATIC indexing (no scratch).
    const float rp0 = sel1 ? p[5] : p[0];
    const float rp1 = sel1 ? p[6] : p[1];
    const float rp2 = sel1 ? p[7] : p[2];
    const float rp3 = sel1 ? p[8] : p[3];
    const float rp4 = sel1 ? p[9] : p[4];
    const float rt0 = sel1 ? t[5] : t[0];
    const float rt1 = sel1 ? t[6] : t[1];
    const float rt2 = sel1 ? t[7] : t[2];
    const float rt3 = sel1 ? t[8] : t[3];

    const float dx = rp0 - rt0;
    const float dy = rp1 - rt1;
    const float l_xy = dx * dx + dy * dy;

    const float sw = sqrtf(rp2) - sqrtf(rt2);
    const float sh = sqrtf(rp3) - sqrtf(rt3);
    const float l_wh = sw * sw + sh * sh;

    const float dobj = rp4 - max_iou;
    const float l_obj = dobj * dobj;

    float l_cls = 0.0f;
#pragma unroll
    for (int c = 10; c < 14; ++c) {
        const float pc = p[c];
        const float tc = t[c];
        l_cls += -(tc * logf(pc) + (1.0f - tc) * logf(1.0f - pc));
    }

    // df loss (unmasked)
    const float q = conf_t;
    const float pp = p[4];
    const float alpha = (1.0f - q) / (1.0f - pp);
    const float l_df = alpha * (pp - q) * logf(pp) + (q - pp) * logf(1.0f - pp);

    return coord * (l_xy + l_wh + l_obj + l_cls) + l_df;
}

__global__ __launch_bounds__(TPB) void yolo_loss_kernel(
    const float* __restrict__ pred, const float* __restrict__ tgt,
    float* __restrict__ partials) {
    __shared__ float4 sp[2][SLOTS];   // 2 x 7 KB
    __shared__ float4 st[2][SLOTS];   // 2 x 7 KB  (28 KB total)

    const int lane = threadIdx.x;     // one wave per block

    const long base4 = (long)blockIdx.x * (2 * SLOTS);  // float4 units
    const float4* __restrict__ gp = reinterpret_cast<const float4*>(pred) + base4;
    const float4* __restrict__ gt = reinterpret_cast<const float4*>(tgt) + base4;

    // Issue tile A then tile B: 14 + 14 gload_lds, each 1 KB coalesced.
#pragma unroll
    for (int h = 0; h < 2; ++h) {
#pragma unroll
        for (int it = 0; it < 7; ++it) {
            const int s = h * SLOTS + it * 64;   // wave-uniform global slot
            const int d = it * 64;               // wave-uniform LDS slot
            __builtin_amdgcn_global_load_lds((glb_void*)(gp + s + lane),
                                             (lds_void*)(&sp[h][d]), 16, 0, 0);
            __builtin_amdgcn_global_load_lds((glb_void*)(gt + s + lane),
                                             (lds_void*)(&st[h][d]), 16, 0, 0);
        }
    }

    float v = 0.0f;

    // ---- half A: wait until only B's 14 loads outstanding ----
    asm volatile("s_waitcnt vmcnt(14)" ::: "memory");
    {
        float lp[28], lt[28];
#pragma unroll
        for (int j = 0; j < 7; ++j) {
            const int s = 7 * lane + j;          // gcd(7,8)=1 -> conflict-free
            reinterpret_cast<float4*>(lp)[j] = sp[0][s];
            reinterpret_cast<float4*>(lt)[j] = st[0][s];
        }
        v += cell_loss(lp, lt) + cell_loss(lp + 14, lt + 14);
    }

    // ---- half B: drain remaining ----
    asm volatile("s_waitcnt vmcnt(0)" ::: "memory");
    {
        float lp[28], lt[28];
#pragma unroll
        for (int j = 0; j < 7; ++j) {
            const int s = 7 * lane + j;
            reinterpret_cast<float4*>(lp)[j] = sp[1][s];
            reinterpret_cast<float4*>(lt)[j] = st[1][s];
        }
        v += cell_loss(lp, lt) + cell_loss(lp + 14, lt + 14);
    }

    // wave-64 reduce, then one plain store per block (no atomics).
#pragma unroll
    for (int off = 32; off > 0; off >>= 1) v += __shfl_down(v, off, 64);
    if (lane == 0) partials[blockIdx.x] = v;
}

__global__ __launch_bounds__(1024) void reduce_kernel(
    const float4* __restrict__ partials4, float* __restrict__ out) {
    // 3136 partials = 784 float4, one per thread (threads >= 784 idle).
    const int tid = threadIdx.x;
    float v = 0.0f;
    if (tid < NBLOCKS / 4) {
        const float4 x = partials4[tid];
        v = (x.x + x.y) + (x.z + x.w);
    }
#pragma unroll
    for (int off = 32; off > 0; off >>= 1) v += __shfl_down(v, off, 64);
    __shared__ float s[16];
    if ((tid & 63) == 0) s[tid >> 6] = v;
    __syncthreads();
    if (tid == 0) {
        float r = 0.0f;
#pragma unroll
        for (int i = 0; i < 16; ++i) r += s[i];
        out[0] = r;
    }
}

extern "C" void kernel_launch(void* const* d_in, const int* in_sizes, int n_in,
                              void* d_out, int out_size, void* d_ws, size_t ws_size,
                              hipStream_t stream) {
    const float* pred = (const float*)d_in[0];
    const float* tgt  = (const float*)d_in[1];
    float* out = (float*)d_out;
    float* partials = (float*)d_ws;   // 3136 * 4 B = 12.5 KB of scratch

    yolo_loss_kernel<<<NBLOCKS, TPB, 0, stream>>>(pred, tgt, partials);
    reduce_kernel<<<1, 1024, 0, stream>>>(
        reinterpret_cast<const float4*>(partials), out);
}